// Round 5
// baseline (918.374 us; speedup 1.0000x reference)
//
#include <hip/hip_runtime.h>

#define N_NODES 100000
#define N_EDGES 1600000
#define D_FEAT  32

// ---- binned fused design ----
#define NB        256                 // dst bins = grid size of fused kernel
#define BIN_NODES 391                 // ceil(N_NODES / NB); last bin has 295
#define CHUNK     65536               // edges scanned per phase
#define NCHUNK    25                  // ceil(N_EDGES / CHUNK)
#define E_PAD     (NCHUNK * CHUNK)    // 1,638,400 (binkey array padded)
#define QCAP      1024                // per-chunk queue; mean fill 256, sigma 16
#define BLOCK_B   512

// Kernel A: binkey[e] = dst[e] / BIN_NODES (u8), padded tail = 0 (rejected
// later by e < N_EDGES check). uchar4 stores -> coalesced.
__global__ void binkey_kernel(const int* __restrict__ dst,
                              uchar4* __restrict__ key4) {
    int i = blockIdx.x * blockDim.x + threadIdx.x;
    if (i >= E_PAD / 4) return;
    int e = i * 4;
    uchar4 k;
    k.x = (e + 0 < N_EDGES) ? (unsigned char)(dst[e + 0] / BIN_NODES) : (unsigned char)0;
    k.y = (e + 1 < N_EDGES) ? (unsigned char)(dst[e + 1] / BIN_NODES) : (unsigned char)0;
    k.z = (e + 2 < N_EDGES) ? (unsigned char)(dst[e + 2] / BIN_NODES) : (unsigned char)0;
    k.w = (e + 3 < N_EDGES) ? (unsigned char)(dst[e + 3] / BIN_NODES) : (unsigned char)0;
    key4[i] = k;
}

// Kernel B: one block per bin. LDS fp32 accumulator for the bin's nodes.
// Per chunk: (scan binkey, enqueue matches) -> barrier -> (half-wave per
// queued edge: coalesced row loads + ds_add_f32). No global atomics, no
// scattered global writes anywhere.
__launch_bounds__(BLOCK_B, 1)
__global__ void sage_bin_fused_kernel(const float* __restrict__ rel,
                                      const float* __restrict__ pattern,
                                      const int* __restrict__ src,
                                      const int* __restrict__ dst,
                                      const unsigned int* __restrict__ key32,
                                      const float4* __restrict__ rel4,
                                      float4* __restrict__ out4) {
    __shared__ float acc[BIN_NODES * D_FEAT];   // 50,048 B
    __shared__ int   degl[BIN_NODES];
    __shared__ int2  queue[QCAP];               // (e, src | ld<<17)
    __shared__ int   qcnt;

    const int b     = blockIdx.x;
    const int tid   = threadIdx.x;
    const int node0 = b * BIN_NODES;

    for (int i = tid; i < BIN_NODES * D_FEAT; i += BLOCK_B) acc[i] = 0.0f;
    for (int i = tid; i < BIN_NODES; i += BLOCK_B) degl[i] = 0;
    if (tid == 0) qcnt = 0;
    __syncthreads();

    const unsigned int bpat = 0x01010101u * (unsigned int)b;
    const int hw = tid >> 5;   // half-wave id 0..15
    const int f  = tid & 31;   // feature lane

    for (int c = 0; c < NCHUNK; ++c) {
        const int ebase = c * CHUNK;

        // ---- scan phase: 16384 key-words per chunk, 32 per thread ----
        for (int w = tid; w < CHUNK / 4; w += BLOCK_B) {
            unsigned int kv = key32[(ebase >> 2) + w];
            unsigned int x  = kv ^ bpat;
            // any-byte-zero prefilter (true for ~6% of words)
            if (((x - 0x01010101u) & ~x & 0x80808080u) != 0u) {
                int e0 = ebase + w * 4;
#pragma unroll
                for (int j = 0; j < 4; ++j) {
                    if (((kv >> (8 * j)) & 255u) == (unsigned int)b) {
                        int e = e0 + j;
                        if (e < N_EDGES) {
                            int ld = dst[e] - node0;     // 0..390
                            int s  = src[e];             // < 2^17
                            int slot = atomicAdd(&qcnt, 1);
                            if (slot < QCAP) {           // astronomically safe
                                queue[slot] = make_int2(e, s | (ld << 17));
                                atomicAdd(&degl[ld], 1);
                            }
                        }
                    }
                }
            }
        }
        __syncthreads();

        // ---- process phase: half-wave per queued edge, 4-wide unroll ----
        int qn = min(qcnt, QCAP);
        int i = hw;
        for (; i + 48 < qn; i += 64) {
            int2 q0 = queue[i], q1 = queue[i + 16], q2 = queue[i + 32], q3 = queue[i + 48];
            int e0 = q0.x, s0 = q0.y & 0x1FFFF, l0 = q0.y >> 17;
            int e1 = q1.x, s1 = q1.y & 0x1FFFF, l1 = q1.y >> 17;
            int e2 = q2.x, s2 = q2.y & 0x1FFFF, l2 = q2.y >> 17;
            int e3 = q3.x, s3 = q3.y & 0x1FFFF, l3 = q3.y >> 17;
            float p0 = pattern[e0 * D_FEAT + f], r0 = rel[s0 * D_FEAT + f];
            float p1 = pattern[e1 * D_FEAT + f], r1 = rel[s1 * D_FEAT + f];
            float p2 = pattern[e2 * D_FEAT + f], r2 = rel[s2 * D_FEAT + f];
            float p3 = pattern[e3 * D_FEAT + f], r3 = rel[s3 * D_FEAT + f];
            atomicAdd(&acc[l0 * D_FEAT + f], p0 * r0);
            atomicAdd(&acc[l1 * D_FEAT + f], p1 * r1);
            atomicAdd(&acc[l2 * D_FEAT + f], p2 * r2);
            atomicAdd(&acc[l3 * D_FEAT + f], p3 * r3);
        }
        for (; i < qn; i += 16) {
            int2 q0 = queue[i];
            int e0 = q0.x, s0 = q0.y & 0x1FFFF, l0 = q0.y >> 17;
            float p0 = pattern[e0 * D_FEAT + f], r0 = rel[s0 * D_FEAT + f];
            atomicAdd(&acc[l0 * D_FEAT + f], p0 * r0);
        }
        __syncthreads();
        if (tid == 0) qcnt = 0;
        __syncthreads();
    }

    // ---- epilogue: out = acc / max(deg,1) + rel, coalesced float4 ----
    int nNodes = min(BIN_NODES, N_NODES - node0);
    for (int i = tid; i < nNodes * 8; i += BLOCK_B) {
        int ld = i >> 3, q = i & 7;
        float4 a = *(const float4*)&acc[ld * D_FEAT + q * 4];
        float inv = 1.0f / fmaxf((float)degl[ld], 1.0f);
        int node = node0 + ld;
        float4 rl = rel4[node * 8 + q];
        float4 o;
        o.x = a.x * inv + rl.x;
        o.y = a.y * inv + rl.y;
        o.z = a.z * inv + rl.z;
        o.w = a.w * inv + rl.w;
        out4[node * 8 + q] = o;
    }
}

// ---- atomic fallback (round-1, known-correct; needs only 400 KB ws) ----
__global__ void sage_edge_atomic_kernel(const float* __restrict__ rel,
                                        const float* __restrict__ pattern,
                                        const int*   __restrict__ src,
                                        const int*   __restrict__ dst,
                                        float* __restrict__ sums,
                                        float* __restrict__ deg) {
    int i = blockIdx.x * blockDim.x + threadIdx.x;
    if (i >= N_EDGES * D_FEAT) return;
    int e = i >> 5;
    int f = i & 31;
    float m = rel[src[e] * D_FEAT + f] * pattern[i];
    atomicAdd(&sums[dst[e] * D_FEAT + f], m);
    if (f == 0) atomicAdd(&deg[dst[e]], 1.0f);
}

__global__ void sage_node_atomic_kernel(const float* __restrict__ rel,
                                        const float* __restrict__ deg,
                                        float* __restrict__ out) {
    int i = blockIdx.x * blockDim.x + threadIdx.x;
    if (i >= N_NODES * D_FEAT) return;
    out[i] = out[i] / fmaxf(deg[i >> 5], 1.0f) + rel[i];
}

extern "C" void kernel_launch(void* const* d_in, const int* in_sizes, int n_in,
                              void* d_out, int out_size, void* d_ws, size_t ws_size,
                              hipStream_t stream) {
    const float* rel     = (const float*)d_in[0];
    const float* pattern = (const float*)d_in[1];
    const int*   src     = (const int*)d_in[2];
    const int*   dst     = (const int*)d_in[3];
    float* out = (float*)d_out;

    if (ws_size >= (size_t)E_PAD) {
        uchar4* key4 = (uchar4*)d_ws;                       // E_PAD bytes
        const unsigned int* key32 = (const unsigned int*)d_ws;

        binkey_kernel<<<(E_PAD / 4 + 255) / 256, 256, 0, stream>>>(dst, key4);

        sage_bin_fused_kernel<<<NB, BLOCK_B, 0, stream>>>(
            rel, pattern, src, dst, key32,
            (const float4*)rel, (float4*)out);
    } else {
        float* deg = (float*)d_ws;
        hipMemsetAsync(out, 0, sizeof(float) * N_NODES * D_FEAT, stream);
        hipMemsetAsync(deg, 0, sizeof(float) * N_NODES, stream);
        sage_edge_atomic_kernel<<<(N_EDGES * D_FEAT + 255) / 256, 256, 0, stream>>>(
            rel, pattern, src, dst, out, deg);
        sage_node_atomic_kernel<<<(N_NODES * D_FEAT + 255) / 256, 256, 0, stream>>>(
            rel, deg, out);
    }
}

// Round 6
// 522.952 us; speedup vs baseline: 1.7561x; 1.7561x over previous
//
#include <hip/hip_runtime.h>

#define N_NODES 100000
#define N_EDGES 1600000
#define D_FEAT  32

// ---- partition parameters ----
#define NBINS     256
#define BIN_NODES 391                 // 256*391 = 100096 >= 100000; bin b covers [b*391, ...)
#define NBLK1     256                 // partition blocks
#define BLK1_T    512
#define CHUNK1    ((N_EDGES + NBLK1 - 1) / NBLK1)   // 6250 edges per block
#define SEGCAP    80                  // records per (block,bin); mean 24.4, +11 sigma
#define BLK2_T    512

// ============ K1: partition into private (block,bin) segments ============
// Private segments => each block appends sequentially to 256 open cachelines
// (16KB active write-set, L2-resident) => writeback ~= data bytes, killing the
// ~0.8-1 TB/s scattered-dirty-line ceiling measured in rounds 1/3/4.
__global__ __launch_bounds__(BLK1_T) void partition_kernel(
    const int* __restrict__ src,
    const int* __restrict__ dst,
    int2* __restrict__ recs,          // [NBLK1 * NBINS * SEGCAP]
    int*  __restrict__ cnt)           // [NBINS * NBLK1] (transposed for K2)
{
    __shared__ int cur[NBINS];
    const int blk = blockIdx.x, tid = threadIdx.x;
    for (int i = tid; i < NBINS; i += BLK1_T) cur[i] = 0;
    __syncthreads();

    const int e0 = blk * CHUNK1;
    const int e1 = min(e0 + CHUNK1, N_EDGES);
    for (int e = e0 + tid; e < e1; e += BLK1_T) {
        int d = dst[e];
        int s = src[e];
        int b  = (int)((unsigned)d / BIN_NODES);     // magic-mul, no div unit needed
        int ld = d - b * BIN_NODES;                  // 0..390
        int slot = atomicAdd(&cur[b], 1);
        if (slot < SEGCAP) {
            // word0: e (21 bits) | ld (9 bits) << 21 ; word1: src
            recs[(size_t)(blk * NBINS + b) * SEGCAP + slot] =
                make_int2((int)((unsigned)e | ((unsigned)ld << 21)), s);
        }
    }
    __syncthreads();
    for (int b = tid; b < NBINS; b += BLK1_T)
        cnt[b * NBLK1 + blk] = min(cur[b], SEGCAP);
}

// ============ K2: per-bin LDS-accumulated gather ============
// One block per bin; 16 half-waves stream their record runs independently
// (no barriers in the main loop). 4-wide unroll => ~8 outstanding 128B row
// loads per half-wave. acc[ld*32+f]: lanes hit banks 0..31, 2 lanes/bank
// across the wave's two half-edges => conflict-free (m136: 2-way is free).
__global__ __launch_bounds__(BLK2_T, 1) void binned_gather_kernel(
    const float*  __restrict__ rel,
    const float*  __restrict__ pattern,
    const int2*   __restrict__ recs,
    const int*    __restrict__ cnt,
    const float4* __restrict__ rel4,
    float4* __restrict__ out4)
{
    __shared__ float acc[BIN_NODES * D_FEAT];   // 50,048 B
    __shared__ int   degl[BIN_NODES];

    const int b   = blockIdx.x;
    const int tid = threadIdx.x;
    for (int i = tid; i < BIN_NODES * D_FEAT; i += BLK2_T) acc[i] = 0.0f;
    for (int i = tid; i < BIN_NODES; i += BLK2_T) degl[i] = 0;
    __syncthreads();

    const int hw = tid >> 5;   // half-wave 0..15
    const int f  = tid & 31;   // feature lane

    for (int r = hw; r < NBLK1; r += 16) {
        int m = cnt[b * NBLK1 + r];
        const int2* rp = recs + (size_t)(r * NBINS + b) * SEGCAP;
        int j = 0;
        for (; j + 4 <= m; j += 4) {
            int2 q0 = rp[j], q1 = rp[j + 1], q2 = rp[j + 2], q3 = rp[j + 3];
            unsigned w0 = (unsigned)q0.x, w1 = (unsigned)q1.x,
                     w2 = (unsigned)q2.x, w3 = (unsigned)q3.x;
            int e0 = w0 & 0x1FFFFF, l0 = w0 >> 21;
            int e1 = w1 & 0x1FFFFF, l1 = w1 >> 21;
            int e2 = w2 & 0x1FFFFF, l2 = w2 >> 21;
            int e3 = w3 & 0x1FFFFF, l3 = w3 >> 21;
            float p0 = pattern[e0 * D_FEAT + f], a0 = rel[q0.y * D_FEAT + f];
            float p1 = pattern[e1 * D_FEAT + f], a1 = rel[q1.y * D_FEAT + f];
            float p2 = pattern[e2 * D_FEAT + f], a2 = rel[q2.y * D_FEAT + f];
            float p3 = pattern[e3 * D_FEAT + f], a3 = rel[q3.y * D_FEAT + f];
            if (f == 0) {
                atomicAdd(&degl[l0], 1); atomicAdd(&degl[l1], 1);
                atomicAdd(&degl[l2], 1); atomicAdd(&degl[l3], 1);
            }
            atomicAdd(&acc[l0 * D_FEAT + f], p0 * a0);
            atomicAdd(&acc[l1 * D_FEAT + f], p1 * a1);
            atomicAdd(&acc[l2 * D_FEAT + f], p2 * a2);
            atomicAdd(&acc[l3 * D_FEAT + f], p3 * a3);
        }
        for (; j < m; ++j) {
            int2 q = rp[j];
            unsigned w = (unsigned)q.x;
            int e = w & 0x1FFFFF, l = w >> 21;
            float p = pattern[e * D_FEAT + f], a = rel[q.y * D_FEAT + f];
            if (f == 0) atomicAdd(&degl[l], 1);
            atomicAdd(&acc[l * D_FEAT + f], p * a);
        }
    }
    __syncthreads();

    // epilogue: out = acc/max(deg,1) + rel, coalesced float4
    const int node0 = b * BIN_NODES;
    const int nNodes = min(BIN_NODES, N_NODES - node0);
    for (int i = tid; i < nNodes * 8; i += BLK2_T) {
        int ld = i >> 3, q = i & 7;
        float4 a = *(const float4*)&acc[ld * D_FEAT + q * 4];
        float inv = 1.0f / fmaxf((float)degl[ld], 1.0f);
        int node = node0 + ld;
        float4 rl = rel4[node * 8 + q];
        float4 o;
        o.x = a.x * inv + rl.x;
        o.y = a.y * inv + rl.y;
        o.z = a.z * inv + rl.z;
        o.w = a.w * inv + rl.w;
        out4[node * 8 + q] = o;
    }
}

// ---- atomic fallback (round-1, known-correct; needs only 400 KB ws) ----
__global__ void sage_edge_atomic_kernel(const float* __restrict__ rel,
                                        const float* __restrict__ pattern,
                                        const int*   __restrict__ src,
                                        const int*   __restrict__ dst,
                                        float* __restrict__ sums,
                                        float* __restrict__ deg) {
    int i = blockIdx.x * blockDim.x + threadIdx.x;
    if (i >= N_EDGES * D_FEAT) return;
    int e = i >> 5;
    int f = i & 31;
    float m = rel[src[e] * D_FEAT + f] * pattern[i];
    atomicAdd(&sums[dst[e] * D_FEAT + f], m);
    if (f == 0) atomicAdd(&deg[dst[e]], 1.0f);
}

__global__ void sage_node_atomic_kernel(const float* __restrict__ rel,
                                        const float* __restrict__ deg,
                                        float* __restrict__ out) {
    int i = blockIdx.x * blockDim.x + threadIdx.x;
    if (i >= N_NODES * D_FEAT) return;
    out[i] = out[i] / fmaxf(deg[i >> 5], 1.0f) + rel[i];
}

extern "C" void kernel_launch(void* const* d_in, const int* in_sizes, int n_in,
                              void* d_out, int out_size, void* d_ws, size_t ws_size,
                              hipStream_t stream) {
    const float* rel     = (const float*)d_in[0];
    const float* pattern = (const float*)d_in[1];
    const int*   src     = (const int*)d_in[2];
    const int*   dst     = (const int*)d_in[3];
    float* out = (float*)d_out;

    const size_t recs_bytes = (size_t)NBLK1 * NBINS * SEGCAP * sizeof(int2); // 41.9 MB
    const size_t cnt_bytes  = (size_t)NBINS * NBLK1 * sizeof(int);           // 256 KB
    const size_t need = recs_bytes + cnt_bytes;

    if (ws_size >= need) {
        int2* recs = (int2*)d_ws;
        int*  cnt  = (int*)((char*)d_ws + recs_bytes);

        partition_kernel<<<NBLK1, BLK1_T, 0, stream>>>(src, dst, recs, cnt);
        binned_gather_kernel<<<NBINS, BLK2_T, 0, stream>>>(
            rel, pattern, recs, cnt, (const float4*)rel, (float4*)out);
    } else {
        float* deg = (float*)d_ws;
        hipMemsetAsync(out, 0, sizeof(float) * N_NODES * D_FEAT, stream);
        hipMemsetAsync(deg, 0, sizeof(float) * N_NODES, stream);
        sage_edge_atomic_kernel<<<(N_EDGES * D_FEAT + 255) / 256, 256, 0, stream>>>(
            rel, pattern, src, dst, out, deg);
        sage_node_atomic_kernel<<<(N_NODES * D_FEAT + 255) / 256, 256, 0, stream>>>(
            rel, deg, out);
    }
}